// Round 15
// baseline (274.356 us; speedup 1.0000x reference)
//
#include <hip/hip_runtime.h>
#include <hip/hip_bf16.h>

#define HID 256
#define IND 21
#define PB 6400      // edges per block in k_part / bhist (R12-proven)
#define MAXB 512     // max buckets (N <= 131072)

typedef short short8 __attribute__((ext_vector_type(8)));
typedef float floatx16 __attribute__((ext_vector_type(16)));
typedef float floatx2 __attribute__((ext_vector_type(2)));

__device__ inline unsigned short f2bf(float f) {
  __hip_bfloat16 h = __float2bfloat16(f);  // RNE
  union { __hip_bfloat16 h; unsigned short u; } c;
  c.h = h;
  return c.u;
}

// pack float2 -> 2 bf16 by truncation (exact for values that came from fp8)
__device__ inline unsigned int pk_bf16_trunc(floatx2 p) {
  union { float f; unsigned int u; } a, b;
  a.f = p.x; b.f = p.y;
  return (b.u & 0xffff0000u) | (a.u >> 16);
}

// accumulate 8 fp8 bytes into 4 packed-f32 accumulators
__device__ inline void acc8p(uint2 v, floatx2* a) {
  a[0] += __builtin_amdgcn_cvt_pk_f32_fp8((int)v.x, false);
  a[1] += __builtin_amdgcn_cvt_pk_f32_fp8((int)v.x, true);
  a[2] += __builtin_amdgcn_cvt_pk_f32_fp8((int)v.y, false);
  a[3] += __builtin_amdgcn_cvt_pk_f32_fp8((int)v.y, true);
}

__device__ inline short8 mk_s8(unsigned a, unsigned b, unsigned c, unsigned d) {
  union { uint4 u; short8 s; } x; x.u = make_uint4(a, b, c, d); return x.s;
}

// decode 8 fp8 bytes (uint2) -> short8 of bf16 (exact)
__device__ inline short8 dec8(uint2 v) {
  unsigned w0 = pk_bf16_trunc(__builtin_amdgcn_cvt_pk_f32_fp8((int)v.x, false));
  unsigned w1 = pk_bf16_trunc(__builtin_amdgcn_cvt_pk_f32_fp8((int)v.x, true));
  unsigned w2 = pk_bf16_trunc(__builtin_amdgcn_cvt_pk_f32_fp8((int)v.y, false));
  unsigned w3 = pk_bf16_trunc(__builtin_amdgcn_cvt_pk_f32_fp8((int)v.y, true));
  return mk_s8(w0, w1, w2, w3);
}

// async global->LDS DMA, 16 B/lane. LDS dest = (uniform) base + lane*16.
__device__ inline void gl16(const unsigned char* g, unsigned char* l) {
  __builtin_amdgcn_global_load_lds(
      (const __attribute__((address_space(1))) unsigned char*)g,
      (__attribute__((address_space(3))) unsigned char*)l, 16, 0, 0);
}

// ---------------------------------------------------------------------------
// fused front kernel: [0,G1) linear_in | [G1,G1+256) wconv | rest bhist
// R15: 16 NODES per linear block (was 8). G1 halves to ~6250 blocks ->
// per-node share of {w[21] reload, 2 barriers, block ramp} halves; per-thread
// FMA doubles (336) raising VALU duty cycle. LDS ~18 KB. Pack: 2 writes/
// thread, k = t*256+tid, j=k>>5, u=k&31 -- lanes 0..31 write consecutive
// xq2 addresses (coalesced). Aqx indexing unchanged (node>>5 / node&31).
// ---------------------------------------------------------------------------
__global__ __launch_bounds__(256) void k_front(
    const float* __restrict__ ns, const float* __restrict__ Win,
    const float* __restrict__ bin, uint2* __restrict__ xq2,
    uint2* __restrict__ Aqx,
    const float* __restrict__ Wself, const float* __restrict__ Wnei,
    unsigned short* __restrict__ Bf16,
    const int* __restrict__ dst, int* __restrict__ bcnt,
    int N, int E, int nb2, int G1) {
  int blk = blockIdx.x;
  int tid = threadIdx.x;
  if (blk < G1) {
    __shared__ __align__(16) float s[16][24];   // 21 used, padded for b128
    __shared__ float fx[16][257];
    int nb = blk * 16;
    for (int idx0 = tid; idx0 < 16 * IND; idx0 += 256) {
      int idx = nb * IND + idx0;
      s[idx0 / IND][idx0 % IND] = (idx < N * IND) ? ns[idx] : 0.f;
    }
    float w[IND];
#pragma unroll
    for (int k = 0; k < IND; k++) w[k] = Win[k * HID + tid];
    float b = bin[tid];
    __syncthreads();
#pragma unroll
    for (int j = 0; j < 16; j++) {
      float acc = b;
      const float4* sp = (const float4*)&s[j][0];
#pragma unroll
      for (int k4 = 0; k4 < 5; k4++) {
        float4 t = sp[k4];
        acc += t.x * w[k4 * 4] + t.y * w[k4 * 4 + 1] +
               t.z * w[k4 * 4 + 2] + t.w * w[k4 * 4 + 3];
      }
      acc += s[j][20] * w[20];
      fx[j][tid] = acc > 0.f ? acc : 0.f;
    }
    __syncthreads();
    // pack: 2 uint2 (8 fp8 each) per thread -> xq (row-major) + Aqx (fragment)
#pragma unroll
    for (int t = 0; t < 2; t++) {
      int k = t * 256 + tid;            // 0..511
      int j = k >> 5, u = k & 31;       // node-local 0..15, unit 0..31
      int node = nb + j;
      if (node < N) {
        const float* fp = &fx[j][u * 8];
        int lo0 = __builtin_amdgcn_cvt_pk_fp8_f32(fp[0], fp[1], 0, false);
        int w0  = __builtin_amdgcn_cvt_pk_fp8_f32(fp[2], fp[3], lo0, true);
        int lo1 = __builtin_amdgcn_cvt_pk_fp8_f32(fp[4], fp[5], 0, false);
        int w1  = __builtin_amdgcn_cvt_pk_fp8_f32(fp[6], fp[7], lo1, true);
        uint2 val = make_uint2((unsigned)w0, (unsigned)w1);
        xq2[(size_t)node * 32 + u] = val;
        int g = node >> 5, row = node & 31, c = u >> 1, hi = u & 1;
        Aqx[(size_t)(g * 16 + c) * 64 + hi * 32 + row] = val;
      }
    }
  } else if (blk < G1 + 256) {
    int n = blk - G1;           // output column 0..255
    int ct = n >> 5, l5 = n & 31;
#pragma unroll
    for (int t = 0; t < 2; t++) {
      int k = tid + t * 256;    // 0..511
      float v = (k < HID) ? Wself[k * HID + n] : Wnei[(k - HID) * HID + n];
      int c = k >> 4, kin = k & 15;
      int lane = (kin >> 3) * 32 + l5;
      int j = kin & 7;
      Bf16[(size_t)((c * 8 + ct) * 64 + lane) * 8 + j] = f2bf(v);
    }
  } else {
    __shared__ int lh[MAXB];
    int e0 = (blk - G1 - 256) * PB;
    for (int b = tid; b < nb2; b += 256) lh[b] = 0;
    __syncthreads();
    int c = min(PB, E - e0);
    for (int i = tid; i < c; i += 256) atomicAdd(&lh[dst[e0 + i] >> 8], 1);
    __syncthreads();
    for (int b = tid; b < nb2; b += 256)
      if (lh[b]) atomicAdd(&bcnt[b], lh[b]);
  }
}

__global__ __launch_bounds__(512) void k_bscan(
    const int* __restrict__ bcnt, int* __restrict__ bbase, int* __restrict__ bcur,
    int* __restrict__ row_start, int E, int N, int nb2) {
  __shared__ int ts[512];
  int tid = threadIdx.x;
  int v = (tid < nb2) ? bcnt[tid] : 0;
  ts[tid] = v;
  __syncthreads();
  for (int off = 1; off < 512; off <<= 1) {
    int t = (tid >= off) ? ts[tid - off] : 0;
    __syncthreads();
    ts[tid] += t;
    __syncthreads();
  }
  if (tid < nb2) { bbase[tid] = ts[tid] - v; bcur[tid] = ts[tid] - v; }
  if (tid == 0) { bbase[nb2] = E; row_start[N] = E; }
}

// partition edges into per-bucket regions of ebuf (bucket = dst>>8).
// ebuf entry packed: (src << 8) | (dst & 255) -- 4 B/edge.
// R14-proven: 1024 threads/block at 250 blocks.
__global__ __launch_bounds__(1024) void k_part(
    const int* __restrict__ src, const int* __restrict__ dst,
    int* __restrict__ bcur, unsigned int* __restrict__ ebuf, int E, int nb2) {
  __shared__ int lh[MAXB];
  int tid = threadIdx.x;
  int e0 = blockIdx.x * PB;
  for (int b = tid; b < nb2; b += 1024) lh[b] = 0;
  __syncthreads();
  int cnt = min(PB, E - e0);
  for (int i = tid; i < cnt; i += 1024) atomicAdd(&lh[dst[e0 + i] >> 8], 1);
  __syncthreads();
  for (int b = tid; b < nb2; b += 1024) {
    int c = lh[b];
    lh[b] = (c > 0) ? atomicAdd(&bcur[b], c) : 0;
  }
  __syncthreads();
  for (int i = tid; i < cnt; i += 1024) {
    int s = src[e0 + i];
    int d = dst[e0 + i];
    int pos = atomicAdd(&lh[d >> 8], 1);
    ebuf[pos] = ((unsigned)s << 8) | ((unsigned)d & 255u);
  }
}

// one block per bucket: LDS count + scan -> row_start; LDS cursors -> csr.
// csr stores the BYTE OFFSET of the source row (src*256 == e & ~255).
// R14-proven: 1024 threads/block (16 waves/bucket).
__global__ __launch_bounds__(1024) void k_fill2(
    const unsigned int* __restrict__ ebuf, const int* __restrict__ bbase,
    int* __restrict__ row_start, unsigned int* __restrict__ csr, int N) {
  __shared__ int lcnt[256];
  __shared__ int lcur[256];
  __shared__ int ts[256];
  int b = blockIdx.x;
  int tid = threadIdx.x;
  int start = bbase[b], end = bbase[b + 1];
  if (tid < 256) lcnt[tid] = 0;
  __syncthreads();
  for (int i = start + tid; i < end; i += 1024)
    atomicAdd(&lcnt[ebuf[i] & 255u], 1);
  __syncthreads();
  if (tid < 256) ts[tid] = lcnt[tid];
  __syncthreads();
  for (int off = 1; off < 256; off <<= 1) {
    int t = 0;
    if (tid < 256 && tid >= off) t = ts[tid - off];
    __syncthreads();
    if (tid < 256) ts[tid] += t;
    __syncthreads();
  }
  if (tid < 256) {
    int v = lcnt[tid];
    int excl = start + ts[tid] - v;
    int node = (b << 8) + tid;
    if (node < N) row_start[node] = excl;
    lcur[tid] = excl;
  }
  __syncthreads();
  for (int i = start + tid; i < end; i += 1024) {
    unsigned int e = ebuf[i];
    int pos = atomicAdd(&lcur[e & 255u], 1);
    csr[pos] = e & ~255u;   // byte offset of source row (src * 256)
  }
}

// ---------------------------------------------------------------------------
// k_agg (R2-best inner loop, UNCHANGED), single launch.
// ---------------------------------------------------------------------------
__global__ __launch_bounds__(256) void k_agg(
    const unsigned char* __restrict__ xqb, const unsigned int* __restrict__ csrb,
    const int* __restrict__ row_start, uint2* __restrict__ Aqagg, int N) {
  __shared__ uint2 ld[8][33];
  int tid = threadIdx.x;
  int lane = tid & 63;
  int w = tid >> 6;
  int half = lane >> 5;
  int l32 = lane & 31;
  unsigned lo = (unsigned)(l32 * 8);

  int nl = w * 2 + half;            // node slot 0..7 within block
  int wid = blockIdx.x * 8 + nl;
  int cw = (wid < N) ? wid : (N - 1);
  int start = row_start[cw];
  int end = row_start[cw + 1];
  int c = end - start;
  floatx2 a[4], b[4], d[4], e[4];
#pragma unroll
  for (int j = 0; j < 4; j++) {
    a[j] = (floatx2){0.f, 0.f}; b[j] = (floatx2){0.f, 0.f};
    d[j] = (floatx2){0.f, 0.f}; e[j] = (floatx2){0.f, 0.f};
  }
  int i = 0;
  while (i < c) {
    int nb = min(32, c - i);
    int sel = (l32 < nb) ? l32 : 0;
    unsigned idx = csrb[start + i + sel];
    int j = 0;
    for (; j + 8 <= nb; j += 8) {
      unsigned o0 = (unsigned)__shfl((int)idx, j + 0, 32) + lo;
      unsigned o1 = (unsigned)__shfl((int)idx, j + 1, 32) + lo;
      unsigned o2 = (unsigned)__shfl((int)idx, j + 2, 32) + lo;
      unsigned o3 = (unsigned)__shfl((int)idx, j + 3, 32) + lo;
      unsigned o4 = (unsigned)__shfl((int)idx, j + 4, 32) + lo;
      unsigned o5 = (unsigned)__shfl((int)idx, j + 5, 32) + lo;
      unsigned o6 = (unsigned)__shfl((int)idx, j + 6, 32) + lo;
      unsigned o7 = (unsigned)__shfl((int)idx, j + 7, 32) + lo;
      uint2 v0 = *(const uint2*)(xqb + o0);
      uint2 v1 = *(const uint2*)(xqb + o1);
      uint2 v2 = *(const uint2*)(xqb + o2);
      uint2 v3 = *(const uint2*)(xqb + o3);
      uint2 v4 = *(const uint2*)(xqb + o4);
      uint2 v5 = *(const uint2*)(xqb + o5);
      uint2 v6 = *(const uint2*)(xqb + o6);
      uint2 v7 = *(const uint2*)(xqb + o7);
      acc8p(v0, a); acc8p(v1, b); acc8p(v2, d); acc8p(v3, e);
      acc8p(v4, a); acc8p(v5, b); acc8p(v6, d); acc8p(v7, e);
    }
    for (; j + 4 <= nb; j += 4) {
      unsigned o0 = (unsigned)__shfl((int)idx, j + 0, 32) + lo;
      unsigned o1 = (unsigned)__shfl((int)idx, j + 1, 32) + lo;
      unsigned o2 = (unsigned)__shfl((int)idx, j + 2, 32) + lo;
      unsigned o3 = (unsigned)__shfl((int)idx, j + 3, 32) + lo;
      uint2 v0 = *(const uint2*)(xqb + o0);
      uint2 v1 = *(const uint2*)(xqb + o1);
      uint2 v2 = *(const uint2*)(xqb + o2);
      uint2 v3 = *(const uint2*)(xqb + o3);
      acc8p(v0, a); acc8p(v1, b); acc8p(v2, d); acc8p(v3, e);
    }
    for (; j < nb; j++) {
      unsigned o0 = (unsigned)__shfl((int)idx, j, 32) + lo;
      uint2 v0 = *(const uint2*)(xqb + o0);
      acc8p(v0, a);
    }
    i += nb;
  }
#pragma unroll
  for (int j = 0; j < 4; j++) a[j] += b[j] + d[j] + e[j];

  float inv = 1.0f / fmaxf((float)c, 1.0f);
  float f[8];
#pragma unroll
  for (int j = 0; j < 4; j++) {
    f[2 * j] = a[j].x * inv;
    f[2 * j + 1] = a[j].y * inv;
  }
  int lo0 = __builtin_amdgcn_cvt_pk_fp8_f32(f[0], f[1], 0, false);
  int w0  = __builtin_amdgcn_cvt_pk_fp8_f32(f[2], f[3], lo0, true);
  int lo1 = __builtin_amdgcn_cvt_pk_fp8_f32(f[4], f[5], 0, false);
  int w1  = __builtin_amdgcn_cvt_pk_fp8_f32(f[6], f[7], lo1, true);
  ld[nl][l32] = make_uint2((unsigned)w0, (unsigned)w1);
  __syncthreads();

  // emit 8-row stripe of fragment-linear group g = blockIdx>>2
  int g = blockIdx.x >> 2;
  int r0 = (blockIdx.x & 3) * 8;
  int s = tid >> 3, j = tid & 7;
  Aqagg[(size_t)g * 1024 + (size_t)s * 32 + r0 + j] = ld[j][s];
}

// ---------------------------------------------------------------------------
// k_h (R12, UNCHANGED): 128-row tile, one barrier, all-A upfront staging,
// B direct from L2 with 1-chunk-ahead register double-buffer.
// C/D: col=lane&31, row=(reg&3)+8*(reg>>2)+4*(lane>>5)  [m74/m101 verified]
// ---------------------------------------------------------------------------
__global__ __launch_bounds__(256, 2) void k_h(
    const unsigned char* __restrict__ Aqx, const unsigned char* __restrict__ Aqagg,
    const unsigned char* __restrict__ Bf8, const float* __restrict__ bself,
    const float* __restrict__ bnei, float* __restrict__ gsum, int N, int nfull) {
  __shared__ __align__(16) unsigned char As[65536];   // 4 grp x 8 ch x 2 KB
  __shared__ float colsum[128];
  int bid = blockIdx.x;
  int bx, by;
  if (bid < nfull) {
    bx = (bid >> 4) * 8 + (bid & 7);
    by = (bid >> 3) & 1;
  } else {
    int rem = bid - nfull;
    bx = (nfull >> 1) + (rem >> 1);
    by = rem & 1;
  }
  int tid = threadIdx.x;
  int lane = tid & 63;
  int w = tid >> 6;
  int wr = w >> 1, wc = w & 1;
  int l32 = lane & 31, half = lane >> 5;
  int rowBase = bx * 128;

  if (tid < 128) colsum[tid] = 0.f;

  floatx16 acc[2][2];
#pragma unroll
  for (int i = 0; i < 2; i++)
#pragma unroll
    for (int j = 0; j < 2; j++) acc[i][j] = (floatx16)(0.f);

  // stage ALL 8 chunks of this block's A: wave w owns row-group w.
  size_t a_grp = (size_t)(bx * 4 + w) * 8192;
  int lb = lane * 16;
#pragma unroll
  for (int ch = 0; ch < 8; ch++) {
    const unsigned char* Aq = (ch < 4) ? Aqx : Aqagg;
    const unsigned char* srcp = Aq + a_grp + (size_t)(ch & 3) * 2048 + lb;
    unsigned char* dstp = As + (size_t)(w * 8 + ch) * 2048;
    gl16(srcp, dstp);
    gl16(srcp + 1024, dstp + 1024);
  }

  // prefetch chunk 0's B into registers (overlaps the A staging DMA)
  size_t bgrp = ((size_t)(by * 4 + wc * 2) * 64 + lane) * 16;
  short8 b0[4], b1[4];
#pragma unroll
  for (int cl = 0; cl < 4; cl++) {
    const unsigned char* bb = Bf8 + bgrp + (size_t)cl * 8192;
    b0[cl] = *(const short8*)bb;
    b1[cl] = *(const short8*)(bb + 1024);
  }

  __syncthreads();   // ONE drain: A staged, colsum init visible

  for (int ch = 0; ch < 8; ch++) {
    short8 n0[4], n1[4];
    if (ch < 7) {
#pragma unroll
      for (int cl = 0; cl < 4; cl++) {
        const unsigned char* bb =
            Bf8 + bgrp + ((size_t)(ch + 1) * 4 + cl) * 8192;
        n0[cl] = *(const short8*)bb;
        n1[cl] = *(const short8*)(bb + 1024);
      }
    }
#pragma unroll
    for (int cl = 0; cl < 4; cl++) {
      short8 afr0 = dec8(*(const uint2*)&As[
          ((size_t)(wr * 2 + 0) * 8 + ch) * 2048 + cl * 512 + lane * 8]);
      short8 afr1 = dec8(*(const uint2*)&As[
          ((size_t)(wr * 2 + 1) * 8 + ch) * 2048 + cl * 512 + lane * 8]);
      acc[0][0] = __builtin_amdgcn_mfma_f32_32x32x16_bf16(afr0, b0[cl], acc[0][0], 0, 0, 0);
      acc[1][0] = __builtin_amdgcn_mfma_f32_32x32x16_bf16(afr1, b0[cl], acc[1][0], 0, 0, 0);
      acc[0][1] = __builtin_amdgcn_mfma_f32_32x32x16_bf16(afr0, b1[cl], acc[0][1], 0, 0, 0);
      acc[1][1] = __builtin_amdgcn_mfma_f32_32x32x16_bf16(afr1, b1[cl], acc[1][1], 0, 0, 0);
    }
    if (ch < 7) {
#pragma unroll
      for (int cl = 0; cl < 4; cl++) { b0[cl] = n0[cl]; b1[cl] = n1[cl]; }
    }
  }

  // epilogue: bias + relu + row-masked column sums -> LDS -> global atomic
#pragma unroll
  for (int ctw = 0; ctw < 2; ctw++) {
    int lcol = (wc * 2 + ctw) * 32 + l32;
    int gcol = by * 128 + lcol;
    float bb = bself[gcol] + bnei[gcol];
    float psum = 0.f;
#pragma unroll
    for (int rt = 0; rt < 2; rt++) {
#pragma unroll
      for (int r = 0; r < 16; r++) {
        int rw = rowBase + wr * 64 + rt * 32 + (r & 3) + 8 * (r >> 2) + 4 * half;
        float v = acc[rt][ctw][r] + bb;
        v = v > 0.f ? v : 0.f;
        if (rw < N) psum += v;
      }
    }
    atomicAdd(&colsum[lcol], psum);   // LDS only (2 adds/col)
  }
  __syncthreads();
  if (tid < 128) atomicAdd(&gsum[by * 128 + tid], colsum[tid]);
}

// ---------------------------------------------------------------------------
// k_out: out = (gsum / N) @ W_out + b_out   single block, 256 threads
// ---------------------------------------------------------------------------
__global__ __launch_bounds__(HID) void k_out(
    const float* __restrict__ gsum, const float* __restrict__ Wout,
    const float* __restrict__ bout, float* __restrict__ out, float invN) {
  __shared__ float g[HID];
  int c = threadIdx.x;
  g[c] = gsum[c] * invN;
  __syncthreads();
  float acc = bout[c];
#pragma unroll 8
  for (int k = 0; k < HID; k++) acc += g[k] * Wout[k * HID + c];
  out[c] = acc;
}

extern "C" void kernel_launch(void* const* d_in, const int* in_sizes, int n_in,
                              void* d_out, int out_size, void* d_ws, size_t ws_size,
                              hipStream_t stream) {
  const float* ns    = (const float*)d_in[0];
  const float* Win   = (const float*)d_in[1];
  const float* bin   = (const float*)d_in[2];
  const float* Wself = (const float*)d_in[3];
  const float* bself = (const float*)d_in[4];
  const float* Wnei  = (const float*)d_in[5];
  const float* bnei  = (const float*)d_in[6];
  const float* Wout  = (const float*)d_in[7];
  const float* bout  = (const float*)d_in[8];
  const int*   eidx  = (const int*)d_in[9];

  int N = in_sizes[0] / IND;
  int E = in_sizes[9] / 2;
  const int* src = eidx;
  const int* dst = eidx + E;
  int nb2 = (N + 255) >> 8;
  int nbx = (N + 127) / 128;                 // k_h row-tiles
  size_t NGU = (size_t)nbx * 4 * 16 * 64;    // fragment uint2 count (padded)

  // ws: xq | Aqx | Aqagg | Bf16 | csr | ebuf | row_start | bcnt | gsum |
  //     bbase | bcur     (bcnt+gsum adjacent -> ONE memset covers both)
  unsigned int* xq     = (unsigned int*)d_ws;
  uint2* Aqx           = (uint2*)(xq + (size_t)N * 64);
  uint2* Aqagg         = Aqx + NGU;
  unsigned short* Bf16 = (unsigned short*)(Aqagg + NGU);
  unsigned int* csr  = (unsigned int*)(Bf16 + 256 * 512);
  unsigned int* ebuf = csr + E;
  int* row_start = (int*)(ebuf + E);
  int* bcnt      = row_start + N + 1;
  float* gsum    = (float*)(bcnt + MAXB);
  int* bbase     = (int*)(gsum + HID);
  int* bcur      = bbase + MAXB + 1;

  hipMemsetAsync(bcnt, 0, (MAXB + HID) * sizeof(int), stream);  // bcnt + gsum

  int G1 = (N + 15) / 16;
  int pgrid = (E + PB - 1) / PB;
  k_front<<<G1 + 256 + pgrid, 256, 0, stream>>>(
      ns, Win, bin, (uint2*)xq, Aqx, Wself, Wnei, Bf16, dst, bcnt,
      N, E, nb2, G1);

  k_bscan<<<1, 512, 0, stream>>>(bcnt, bbase, bcur, row_start, E, N, nb2);
  k_part<<<pgrid, 1024, 0, stream>>>(src, dst, bcur, ebuf, E, nb2);
  k_fill2<<<nb2, 1024, 0, stream>>>(ebuf, bbase, row_start, csr, N);

  int agrid = (N + 7) / 8;
  k_agg<<<agrid, 256, 0, stream>>>((const unsigned char*)xq, csr, row_start,
                                   Aqagg, N);

  int nblocks = nbx * 2;
  int nfull = (nblocks / 16) * 16;
  k_h<<<nblocks, 256, 0, stream>>>((const unsigned char*)Aqx,
                                   (const unsigned char*)Aqagg,
                                   (const unsigned char*)Bf16,
                                   bself, bnei, gsum, N, nfull);

  k_out<<<1, HID, 0, stream>>>(gsum, Wout, bout, (float*)d_out, 1.0f / (float)N);
}

// Round 16
// 268.625 us; speedup vs baseline: 1.0213x; 1.0213x over previous
//
#include <hip/hip_runtime.h>
#include <hip/hip_bf16.h>

#define HID 256
#define IND 21
#define PB 6400      // edges per block in k_part / bhist (R12-proven)
#define MAXB 512     // max buckets (N <= 131072)

typedef short short8 __attribute__((ext_vector_type(8)));
typedef float floatx16 __attribute__((ext_vector_type(16)));
typedef float floatx2 __attribute__((ext_vector_type(2)));

__device__ inline unsigned short f2bf(float f) {
  __hip_bfloat16 h = __float2bfloat16(f);  // RNE
  union { __hip_bfloat16 h; unsigned short u; } c;
  c.h = h;
  return c.u;
}

// pack float2 -> 2 bf16 by truncation (exact for values that came from fp8)
__device__ inline unsigned int pk_bf16_trunc(floatx2 p) {
  union { float f; unsigned int u; } a, b;
  a.f = p.x; b.f = p.y;
  return (b.u & 0xffff0000u) | (a.u >> 16);
}

// accumulate 8 fp8 bytes into 4 packed-f32 accumulators
__device__ inline void acc8p(uint2 v, floatx2* a) {
  a[0] += __builtin_amdgcn_cvt_pk_f32_fp8((int)v.x, false);
  a[1] += __builtin_amdgcn_cvt_pk_f32_fp8((int)v.x, true);
  a[2] += __builtin_amdgcn_cvt_pk_f32_fp8((int)v.y, false);
  a[3] += __builtin_amdgcn_cvt_pk_f32_fp8((int)v.y, true);
}

__device__ inline short8 mk_s8(unsigned a, unsigned b, unsigned c, unsigned d) {
  union { uint4 u; short8 s; } x; x.u = make_uint4(a, b, c, d); return x.s;
}

// decode 8 fp8 bytes (uint2) -> short8 of bf16 (exact)
__device__ inline short8 dec8(uint2 v) {
  unsigned w0 = pk_bf16_trunc(__builtin_amdgcn_cvt_pk_f32_fp8((int)v.x, false));
  unsigned w1 = pk_bf16_trunc(__builtin_amdgcn_cvt_pk_f32_fp8((int)v.x, true));
  unsigned w2 = pk_bf16_trunc(__builtin_amdgcn_cvt_pk_f32_fp8((int)v.y, false));
  unsigned w3 = pk_bf16_trunc(__builtin_amdgcn_cvt_pk_f32_fp8((int)v.y, true));
  return mk_s8(w0, w1, w2, w3);
}

// async global->LDS DMA, 16 B/lane. LDS dest = (uniform) base + lane*16.
__device__ inline void gl16(const unsigned char* g, unsigned char* l) {
  __builtin_amdgcn_global_load_lds(
      (const __attribute__((address_space(1))) unsigned char*)g,
      (__attribute__((address_space(3))) unsigned char*)l, 16, 0, 0);
}

// ---------------------------------------------------------------------------
// fused front kernel: [0,G1) linear_in | [G1,G1+256) wconv | rest bhist
// (R14-proven: 8 nodes/block; R15 showed 16-node variant regresses via
// LDS-occupancy loss + serial per-thread node chain.)
// ---------------------------------------------------------------------------
__global__ __launch_bounds__(256) void k_front(
    const float* __restrict__ ns, const float* __restrict__ Win,
    const float* __restrict__ bin, uint2* __restrict__ xq2,
    uint2* __restrict__ Aqx,
    const float* __restrict__ Wself, const float* __restrict__ Wnei,
    unsigned short* __restrict__ Bf16,
    const int* __restrict__ dst, int* __restrict__ bcnt,
    int N, int E, int nb2, int G1) {
  int blk = blockIdx.x;
  int tid = threadIdx.x;
  if (blk < G1) {
    __shared__ __align__(16) float s[8][24];   // 21 used, padded for b128
    __shared__ float fx[8][257];
    int nb = blk * 8;
    if (tid < 8 * IND) {
      int idx = nb * IND + tid;
      s[tid / IND][tid % IND] = (idx < N * IND) ? ns[idx] : 0.f;
    }
    float w[IND];
#pragma unroll
    for (int k = 0; k < IND; k++) w[k] = Win[k * HID + tid];
    float b = bin[tid];
    __syncthreads();
#pragma unroll
    for (int j = 0; j < 8; j++) {
      float acc = b;
      const float4* sp = (const float4*)&s[j][0];
#pragma unroll
      for (int k4 = 0; k4 < 5; k4++) {
        float4 t = sp[k4];
        acc += t.x * w[k4 * 4] + t.y * w[k4 * 4 + 1] +
               t.z * w[k4 * 4 + 2] + t.w * w[k4 * 4 + 3];
      }
      acc += s[j][20] * w[20];
      fx[j][tid] = acc > 0.f ? acc : 0.f;
    }
    __syncthreads();
    // pack: one uint2 (8 fp8) per thread -> xq (row-major) + Aqx (fragment)
    {
      int j = tid & 7, u = tid >> 3;    // node-local, 8-col unit 0..31
      int node = nb + j;
      if (node < N) {
        const float* fp = &fx[j][u * 8];
        int lo0 = __builtin_amdgcn_cvt_pk_fp8_f32(fp[0], fp[1], 0, false);
        int w0  = __builtin_amdgcn_cvt_pk_fp8_f32(fp[2], fp[3], lo0, true);
        int lo1 = __builtin_amdgcn_cvt_pk_fp8_f32(fp[4], fp[5], 0, false);
        int w1  = __builtin_amdgcn_cvt_pk_fp8_f32(fp[6], fp[7], lo1, true);
        uint2 val = make_uint2((unsigned)w0, (unsigned)w1);
        xq2[(size_t)node * 32 + u] = val;
        int g = node >> 5, row = node & 31, c = u >> 1, hi = u & 1;
        Aqx[(size_t)(g * 16 + c) * 64 + hi * 32 + row] = val;
      }
    }
  } else if (blk < G1 + 256) {
    int n = blk - G1;           // output column 0..255
    int ct = n >> 5, l5 = n & 31;
#pragma unroll
    for (int t = 0; t < 2; t++) {
      int k = tid + t * 256;    // 0..511
      float v = (k < HID) ? Wself[k * HID + n] : Wnei[(k - HID) * HID + n];
      int c = k >> 4, kin = k & 15;
      int lane = (kin >> 3) * 32 + l5;
      int j = kin & 7;
      Bf16[(size_t)((c * 8 + ct) * 64 + lane) * 8 + j] = f2bf(v);
    }
  } else {
    __shared__ int lh[MAXB];
    int e0 = (blk - G1 - 256) * PB;
    for (int b = tid; b < nb2; b += 256) lh[b] = 0;
    __syncthreads();
    int c = min(PB, E - e0);
    for (int i = tid; i < c; i += 256) atomicAdd(&lh[dst[e0 + i] >> 8], 1);
    __syncthreads();
    for (int b = tid; b < nb2; b += 256)
      if (lh[b]) atomicAdd(&bcnt[b], lh[b]);
  }
}

__global__ __launch_bounds__(512) void k_bscan(
    const int* __restrict__ bcnt, int* __restrict__ bbase, int* __restrict__ bcur,
    int* __restrict__ row_start, int E, int N, int nb2) {
  __shared__ int ts[512];
  int tid = threadIdx.x;
  int v = (tid < nb2) ? bcnt[tid] : 0;
  ts[tid] = v;
  __syncthreads();
  for (int off = 1; off < 512; off <<= 1) {
    int t = (tid >= off) ? ts[tid - off] : 0;
    __syncthreads();
    ts[tid] += t;
    __syncthreads();
  }
  if (tid < nb2) { bbase[tid] = ts[tid] - v; bcur[tid] = ts[tid] - v; }
  if (tid == 0) { bbase[nb2] = E; row_start[N] = E; }
}

// partition edges into per-bucket regions of ebuf (bucket = dst>>8).
// ebuf entry packed: (src << 8) | (dst & 255) -- 4 B/edge.
// R14-proven: 1024 threads/block at 250 blocks.
__global__ __launch_bounds__(1024) void k_part(
    const int* __restrict__ src, const int* __restrict__ dst,
    int* __restrict__ bcur, unsigned int* __restrict__ ebuf, int E, int nb2) {
  __shared__ int lh[MAXB];
  int tid = threadIdx.x;
  int e0 = blockIdx.x * PB;
  for (int b = tid; b < nb2; b += 1024) lh[b] = 0;
  __syncthreads();
  int cnt = min(PB, E - e0);
  for (int i = tid; i < cnt; i += 1024) atomicAdd(&lh[dst[e0 + i] >> 8], 1);
  __syncthreads();
  for (int b = tid; b < nb2; b += 1024) {
    int c = lh[b];
    lh[b] = (c > 0) ? atomicAdd(&bcur[b], c) : 0;
  }
  __syncthreads();
  for (int i = tid; i < cnt; i += 1024) {
    int s = src[e0 + i];
    int d = dst[e0 + i];
    int pos = atomicAdd(&lh[d >> 8], 1);
    ebuf[pos] = ((unsigned)s << 8) | ((unsigned)d & 255u);
  }
}

// one block per bucket: LDS count + scan -> row_start; LDS cursors -> csr.
// csr stores the BYTE OFFSET of the source row (src*256 == e & ~255).
// R14-proven: 1024 threads/block (16 waves/bucket).
__global__ __launch_bounds__(1024) void k_fill2(
    const unsigned int* __restrict__ ebuf, const int* __restrict__ bbase,
    int* __restrict__ row_start, unsigned int* __restrict__ csr, int N) {
  __shared__ int lcnt[256];
  __shared__ int lcur[256];
  __shared__ int ts[256];
  int b = blockIdx.x;
  int tid = threadIdx.x;
  int start = bbase[b], end = bbase[b + 1];
  if (tid < 256) lcnt[tid] = 0;
  __syncthreads();
  for (int i = start + tid; i < end; i += 1024)
    atomicAdd(&lcnt[ebuf[i] & 255u], 1);
  __syncthreads();
  if (tid < 256) ts[tid] = lcnt[tid];
  __syncthreads();
  for (int off = 1; off < 256; off <<= 1) {
    int t = 0;
    if (tid < 256 && tid >= off) t = ts[tid - off];
    __syncthreads();
    if (tid < 256) ts[tid] += t;
    __syncthreads();
  }
  if (tid < 256) {
    int v = lcnt[tid];
    int excl = start + ts[tid] - v;
    int node = (b << 8) + tid;
    if (node < N) row_start[node] = excl;
    lcur[tid] = excl;
  }
  __syncthreads();
  for (int i = start + tid; i < end; i += 1024) {
    unsigned int e = ebuf[i];
    int pos = atomicAdd(&lcur[e & 255u], 1);
    csr[pos] = e & ~255u;   // byte offset of source row (src * 256)
  }
}

// ---------------------------------------------------------------------------
// k_agg (R2-best inner loop, UNCHANGED), single launch. At its latency x
// concurrency floor: logical 410 MB / 57.6 us = 7.1 TB/s, matching Little's
// law for ~2.3 MB in flight at ~700 cy mixed L2/L3 latency.
// ---------------------------------------------------------------------------
__global__ __launch_bounds__(256) void k_agg(
    const unsigned char* __restrict__ xqb, const unsigned int* __restrict__ csrb,
    const int* __restrict__ row_start, uint2* __restrict__ Aqagg, int N) {
  __shared__ uint2 ld[8][33];
  int tid = threadIdx.x;
  int lane = tid & 63;
  int w = tid >> 6;
  int half = lane >> 5;
  int l32 = lane & 31;
  unsigned lo = (unsigned)(l32 * 8);

  int nl = w * 2 + half;            // node slot 0..7 within block
  int wid = blockIdx.x * 8 + nl;
  int cw = (wid < N) ? wid : (N - 1);
  int start = row_start[cw];
  int end = row_start[cw + 1];
  int c = end - start;
  floatx2 a[4], b[4], d[4], e[4];
#pragma unroll
  for (int j = 0; j < 4; j++) {
    a[j] = (floatx2){0.f, 0.f}; b[j] = (floatx2){0.f, 0.f};
    d[j] = (floatx2){0.f, 0.f}; e[j] = (floatx2){0.f, 0.f};
  }
  int i = 0;
  while (i < c) {
    int nb = min(32, c - i);
    int sel = (l32 < nb) ? l32 : 0;
    unsigned idx = csrb[start + i + sel];
    int j = 0;
    for (; j + 8 <= nb; j += 8) {
      unsigned o0 = (unsigned)__shfl((int)idx, j + 0, 32) + lo;
      unsigned o1 = (unsigned)__shfl((int)idx, j + 1, 32) + lo;
      unsigned o2 = (unsigned)__shfl((int)idx, j + 2, 32) + lo;
      unsigned o3 = (unsigned)__shfl((int)idx, j + 3, 32) + lo;
      unsigned o4 = (unsigned)__shfl((int)idx, j + 4, 32) + lo;
      unsigned o5 = (unsigned)__shfl((int)idx, j + 5, 32) + lo;
      unsigned o6 = (unsigned)__shfl((int)idx, j + 6, 32) + lo;
      unsigned o7 = (unsigned)__shfl((int)idx, j + 7, 32) + lo;
      uint2 v0 = *(const uint2*)(xqb + o0);
      uint2 v1 = *(const uint2*)(xqb + o1);
      uint2 v2 = *(const uint2*)(xqb + o2);
      uint2 v3 = *(const uint2*)(xqb + o3);
      uint2 v4 = *(const uint2*)(xqb + o4);
      uint2 v5 = *(const uint2*)(xqb + o5);
      uint2 v6 = *(const uint2*)(xqb + o6);
      uint2 v7 = *(const uint2*)(xqb + o7);
      acc8p(v0, a); acc8p(v1, b); acc8p(v2, d); acc8p(v3, e);
      acc8p(v4, a); acc8p(v5, b); acc8p(v6, d); acc8p(v7, e);
    }
    for (; j + 4 <= nb; j += 4) {
      unsigned o0 = (unsigned)__shfl((int)idx, j + 0, 32) + lo;
      unsigned o1 = (unsigned)__shfl((int)idx, j + 1, 32) + lo;
      unsigned o2 = (unsigned)__shfl((int)idx, j + 2, 32) + lo;
      unsigned o3 = (unsigned)__shfl((int)idx, j + 3, 32) + lo;
      uint2 v0 = *(const uint2*)(xqb + o0);
      uint2 v1 = *(const uint2*)(xqb + o1);
      uint2 v2 = *(const uint2*)(xqb + o2);
      uint2 v3 = *(const uint2*)(xqb + o3);
      acc8p(v0, a); acc8p(v1, b); acc8p(v2, d); acc8p(v3, e);
    }
    for (; j < nb; j++) {
      unsigned o0 = (unsigned)__shfl((int)idx, j, 32) + lo;
      uint2 v0 = *(const uint2*)(xqb + o0);
      acc8p(v0, a);
    }
    i += nb;
  }
#pragma unroll
  for (int j = 0; j < 4; j++) a[j] += b[j] + d[j] + e[j];

  float inv = 1.0f / fmaxf((float)c, 1.0f);
  float f[8];
#pragma unroll
  for (int j = 0; j < 4; j++) {
    f[2 * j] = a[j].x * inv;
    f[2 * j + 1] = a[j].y * inv;
  }
  int lo0 = __builtin_amdgcn_cvt_pk_fp8_f32(f[0], f[1], 0, false);
  int w0  = __builtin_amdgcn_cvt_pk_fp8_f32(f[2], f[3], lo0, true);
  int lo1 = __builtin_amdgcn_cvt_pk_fp8_f32(f[4], f[5], 0, false);
  int w1  = __builtin_amdgcn_cvt_pk_fp8_f32(f[6], f[7], lo1, true);
  ld[nl][l32] = make_uint2((unsigned)w0, (unsigned)w1);
  __syncthreads();

  // emit 8-row stripe of fragment-linear group g = blockIdx>>2
  int g = blockIdx.x >> 2;
  int r0 = (blockIdx.x & 3) * 8;
  int s = tid >> 3, j = tid & 7;
  Aqagg[(size_t)g * 1024 + (size_t)s * 32 + r0 + j] = ld[j][s];
}

// ---------------------------------------------------------------------------
// k_h (R12, UNCHANGED): 128-row tile, one barrier, all-A upfront staging,
// B direct from L2 with 1-chunk-ahead register double-buffer.
// C/D: col=lane&31, row=(reg&3)+8*(reg>>2)+4*(lane>>5)  [m74/m101 verified]
// ---------------------------------------------------------------------------
__global__ __launch_bounds__(256, 2) void k_h(
    const unsigned char* __restrict__ Aqx, const unsigned char* __restrict__ Aqagg,
    const unsigned char* __restrict__ Bf8, const float* __restrict__ bself,
    const float* __restrict__ bnei, float* __restrict__ gsum, int N, int nfull) {
  __shared__ __align__(16) unsigned char As[65536];   // 4 grp x 8 ch x 2 KB
  __shared__ float colsum[128];
  int bid = blockIdx.x;
  int bx, by;
  if (bid < nfull) {
    bx = (bid >> 4) * 8 + (bid & 7);
    by = (bid >> 3) & 1;
  } else {
    int rem = bid - nfull;
    bx = (nfull >> 1) + (rem >> 1);
    by = rem & 1;
  }
  int tid = threadIdx.x;
  int lane = tid & 63;
  int w = tid >> 6;
  int wr = w >> 1, wc = w & 1;
  int l32 = lane & 31, half = lane >> 5;
  int rowBase = bx * 128;

  if (tid < 128) colsum[tid] = 0.f;

  floatx16 acc[2][2];
#pragma unroll
  for (int i = 0; i < 2; i++)
#pragma unroll
    for (int j = 0; j < 2; j++) acc[i][j] = (floatx16)(0.f);

  // stage ALL 8 chunks of this block's A: wave w owns row-group w.
  size_t a_grp = (size_t)(bx * 4 + w) * 8192;
  int lb = lane * 16;
#pragma unroll
  for (int ch = 0; ch < 8; ch++) {
    const unsigned char* Aq = (ch < 4) ? Aqx : Aqagg;
    const unsigned char* srcp = Aq + a_grp + (size_t)(ch & 3) * 2048 + lb;
    unsigned char* dstp = As + (size_t)(w * 8 + ch) * 2048;
    gl16(srcp, dstp);
    gl16(srcp + 1024, dstp + 1024);
  }

  // prefetch chunk 0's B into registers (overlaps the A staging DMA)
  size_t bgrp = ((size_t)(by * 4 + wc * 2) * 64 + lane) * 16;
  short8 b0[4], b1[4];
#pragma unroll
  for (int cl = 0; cl < 4; cl++) {
    const unsigned char* bb = Bf8 + bgrp + (size_t)cl * 8192;
    b0[cl] = *(const short8*)bb;
    b1[cl] = *(const short8*)(bb + 1024);
  }

  __syncthreads();   // ONE drain: A staged, colsum init visible

  for (int ch = 0; ch < 8; ch++) {
    short8 n0[4], n1[4];
    if (ch < 7) {
#pragma unroll
      for (int cl = 0; cl < 4; cl++) {
        const unsigned char* bb =
            Bf8 + bgrp + ((size_t)(ch + 1) * 4 + cl) * 8192;
        n0[cl] = *(const short8*)bb;
        n1[cl] = *(const short8*)(bb + 1024);
      }
    }
#pragma unroll
    for (int cl = 0; cl < 4; cl++) {
      short8 afr0 = dec8(*(const uint2*)&As[
          ((size_t)(wr * 2 + 0) * 8 + ch) * 2048 + cl * 512 + lane * 8]);
      short8 afr1 = dec8(*(const uint2*)&As[
          ((size_t)(wr * 2 + 1) * 8 + ch) * 2048 + cl * 512 + lane * 8]);
      acc[0][0] = __builtin_amdgcn_mfma_f32_32x32x16_bf16(afr0, b0[cl], acc[0][0], 0, 0, 0);
      acc[1][0] = __builtin_amdgcn_mfma_f32_32x32x16_bf16(afr1, b0[cl], acc[1][0], 0, 0, 0);
      acc[0][1] = __builtin_amdgcn_mfma_f32_32x32x16_bf16(afr0, b1[cl], acc[0][1], 0, 0, 0);
      acc[1][1] = __builtin_amdgcn_mfma_f32_32x32x16_bf16(afr1, b1[cl], acc[1][1], 0, 0, 0);
    }
    if (ch < 7) {
#pragma unroll
      for (int cl = 0; cl < 4; cl++) { b0[cl] = n0[cl]; b1[cl] = n1[cl]; }
    }
  }

  // epilogue: bias + relu + row-masked column sums -> LDS -> global atomic
#pragma unroll
  for (int ctw = 0; ctw < 2; ctw++) {
    int lcol = (wc * 2 + ctw) * 32 + l32;
    int gcol = by * 128 + lcol;
    float bb = bself[gcol] + bnei[gcol];
    float psum = 0.f;
#pragma unroll
    for (int rt = 0; rt < 2; rt++) {
#pragma unroll
      for (int r = 0; r < 16; r++) {
        int rw = rowBase + wr * 64 + rt * 32 + (r & 3) + 8 * (r >> 2) + 4 * half;
        float v = acc[rt][ctw][r] + bb;
        v = v > 0.f ? v : 0.f;
        if (rw < N) psum += v;
      }
    }
    atomicAdd(&colsum[lcol], psum);   // LDS only (2 adds/col)
  }
  __syncthreads();
  if (tid < 128) atomicAdd(&gsum[by * 128 + tid], colsum[tid]);
}

// ---------------------------------------------------------------------------
// k_out: out = (gsum / N) @ W_out + b_out   single block, 256 threads
// ---------------------------------------------------------------------------
__global__ __launch_bounds__(HID) void k_out(
    const float* __restrict__ gsum, const float* __restrict__ Wout,
    const float* __restrict__ bout, float* __restrict__ out, float invN) {
  __shared__ float g[HID];
  int c = threadIdx.x;
  g[c] = gsum[c] * invN;
  __syncthreads();
  float acc = bout[c];
#pragma unroll 8
  for (int k = 0; k < HID; k++) acc += g[k] * Wout[k * HID + c];
  out[c] = acc;
}

extern "C" void kernel_launch(void* const* d_in, const int* in_sizes, int n_in,
                              void* d_out, int out_size, void* d_ws, size_t ws_size,
                              hipStream_t stream) {
  const float* ns    = (const float*)d_in[0];
  const float* Win   = (const float*)d_in[1];
  const float* bin   = (const float*)d_in[2];
  const float* Wself = (const float*)d_in[3];
  const float* bself = (const float*)d_in[4];
  const float* Wnei  = (const float*)d_in[5];
  const float* bnei  = (const float*)d_in[6];
  const float* Wout  = (const float*)d_in[7];
  const float* bout  = (const float*)d_in[8];
  const int*   eidx  = (const int*)d_in[9];

  int N = in_sizes[0] / IND;
  int E = in_sizes[9] / 2;
  const int* src = eidx;
  const int* dst = eidx + E;
  int nb2 = (N + 255) >> 8;
  int nbx = (N + 127) / 128;                 // k_h row-tiles
  size_t NGU = (size_t)nbx * 4 * 16 * 64;    // fragment uint2 count (padded)

  // ws: xq | Aqx | Aqagg | Bf16 | csr | ebuf | row_start | bcnt | gsum |
  //     bbase | bcur     (bcnt+gsum adjacent -> ONE memset covers both)
  unsigned int* xq     = (unsigned int*)d_ws;
  uint2* Aqx           = (uint2*)(xq + (size_t)N * 64);
  uint2* Aqagg         = Aqx + NGU;
  unsigned short* Bf16 = (unsigned short*)(Aqagg + NGU);
  unsigned int* csr  = (unsigned int*)(Bf16 + 256 * 512);
  unsigned int* ebuf = csr + E;
  int* row_start = (int*)(ebuf + E);
  int* bcnt      = row_start + N + 1;
  float* gsum    = (float*)(bcnt + MAXB);
  int* bbase     = (int*)(gsum + HID);
  int* bcur      = bbase + MAXB + 1;

  hipMemsetAsync(bcnt, 0, (MAXB + HID) * sizeof(int), stream);  // bcnt + gsum

  int G1 = (N + 7) / 8;
  int pgrid = (E + PB - 1) / PB;
  k_front<<<G1 + 256 + pgrid, 256, 0, stream>>>(
      ns, Win, bin, (uint2*)xq, Aqx, Wself, Wnei, Bf16, dst, bcnt,
      N, E, nb2, G1);

  k_bscan<<<1, 512, 0, stream>>>(bcnt, bbase, bcur, row_start, E, N, nb2);
  k_part<<<pgrid, 1024, 0, stream>>>(src, dst, bcur, ebuf, E, nb2);
  k_fill2<<<nb2, 1024, 0, stream>>>(ebuf, bbase, row_start, csr, N);

  int agrid = (N + 7) / 8;
  k_agg<<<agrid, 256, 0, stream>>>((const unsigned char*)xq, csr, row_start,
                                   Aqagg, N);

  int nblocks = nbx * 2;
  int nfull = (nblocks / 16) * 16;
  k_h<<<nblocks, 256, 0, stream>>>((const unsigned char*)Aqx,
                                   (const unsigned char*)Aqagg,
                                   (const unsigned char*)Bf16,
                                   bself, bnei, gsum, N, nfull);

  k_out<<<1, HID, 0, stream>>>(gsum, Wout, bout, (float*)d_out, 1.0f / (float)N);
}